// Round 9
// baseline (624.745 us; speedup 1.0000x reference)
//
#include <hip/hip_runtime.h>
#include <hip/hip_bf16.h>

// Problem constants (B=8192, D=128 from reference setup_inputs)
constexpr int Bh = 8192;
constexpr int Nn = 16384;   // 2*B
constexpr int Dd = 128;
constexpr float EPS = 1e-8f;
constexpr float LN2 = 0.69314718056f;

constexpr int N_TILES = 8256;      // upper-triangle 128x128 tiles: sum_{b=0}^{127}(128-b)

typedef short bf16x8 __attribute__((ext_vector_type(8)));
typedef float f32x4 __attribute__((ext_vector_type(4)));

// ---- Kernel 1: fp32 -> bf16, scaled by sqrt(2*log2e) so MFMA dot == sim/tau*log2e ----
__global__ __launch_bounds__(256) void convert_kernel(const float4* __restrict__ za,
                                                      const float4* __restrict__ zb,
                                                      ushort* __restrict__ z,
                                                      float* __restrict__ rowsum,
                                                      int* __restrict__ cnt) {
    const int t = blockIdx.x * 256 + threadIdx.x;        // 0 .. 524287
    constexpr int Q = (Bh * Dd) / 4;                     // 262144 float4 per input
    const float SCL = 1.69864363f;                       // sqrt(2 * 1.4426950409)
    float4 v = (t < Q) ? za[t] : zb[t - Q];
    union { ushort4 u4; __hip_bfloat16 h[4]; } cv;
    cv.h[0] = __float2bfloat16(v.x * SCL);
    cv.h[1] = __float2bfloat16(v.y * SCL);
    cv.h[2] = __float2bfloat16(v.z * SCL);
    cv.h[3] = __float2bfloat16(v.w * SCL);
    ((ushort4*)z)[t] = cv.u4;
    if (t < Nn) rowsum[t] = 0.f;
    if (t == 0) *cnt = 0;    // last-block-done counter
}

// tile g -> 128-row block b: largest b with cum(b) = b*(257-b)/2 <= g
__device__ __forceinline__ int row_block_of128(int g) {
    int b = (int)((257.0f - sqrtf((float)(66049 - 8 * g))) * 0.5f);
    b = b < 0 ? 0 : (b > 127 ? 127 : b);
    while (b * (257 - b) / 2 > g) --b;
    while ((b + 1) * (256 - b) / 2 <= g) ++b;
    return b;
}

// ---- Kernel 2: one 128x128 upper-triangle tile per 256-thread block (4 waves x 32 rows).
// B-tile staged once to LDS via global_load_lds (16B, no VGPR round-trip) in an
// XOR-swizzled chunk layout: LDS slot s holds global chunk (col=s>>4, ci=(s&15)^(col&15)).
// The swizzle makes ds_read_b128 conflict-free (R5 measured 0 conflicts) AND — since
// global_load_lds cannot scatter — is realized by PERMUTING the per-lane global fetch.
// K-loop ds_read addresses = per-lane base[kt] + st*4096 (16-bit immediates): ZERO
// address VALU in the hot loop (R4-R8 lesson: wall scales ~1/resident-waves; busy-VALU
// was dominated by per-st address math, not softplus).
// Product-softplus: softplus2(u)=max(u,0)+log2(t), t=1+2^-|u|; one exp2/element, logs
// deferred (8/tile row-side, 1 per 16-col group/st col-side).
// NOTE: plain __launch_bounds__(256); min-waves args (R1/R5) clamp unified VGPR+AGPR
// to 64/128 and spill ~GBs to scratch.
__global__ __launch_bounds__(256) void main_kernel(const ushort* __restrict__ z,
                                                   float* __restrict__ rowsum,
                                                   float* __restrict__ pospair,
                                                   int* __restrict__ cnt,
                                                   float* __restrict__ out) {
    __shared__ ushort ldsB[128 * 128];   // 32 KB, swizzled 16B chunks

    const int tid = threadIdx.x;
    const int wave = tid >> 6;
    const int lane = tid & 63;
    const int q = lane >> 4;        // quad: 0..3
    const int c = lane & 15;        // 0..15

    const int g = blockIdx.x;
    const int b = row_block_of128(g);
    const int ct = b + (g - b * (257 - b) / 2);   // ct >= b always (upper triangle)
    const int C0 = ct << 7;
    const int rowW = (b << 7) + wave * 32;
    const bool diag = (ct == b);

    // A fragments: 2 row-sets x 4 k-tiles (32 VGPRs); issued first, in flight
    // through staging + barrier.
    bf16x8 afrag[2][4];
#pragma unroll
    for (int s = 0; s < 2; ++s) {
        const ushort* ap = z + (size_t)(rowW + s * 16 + c) * Dd;
#pragma unroll
        for (int kt = 0; kt < 4; ++kt)
            afrag[s][kt] = *(const bf16x8*)(ap + kt * 32 + q * 8);
    }

    // stage B tile: 2048 16B chunks / 256 threads = 8 global_load_lds each.
    // slot sN -> LDS byte sN*16; fetches global chunk ci = (sN&15) ^ (col&15).
#pragma unroll
    for (int it = 0; it < 8; ++it) {
        int sN = it * 256 + tid;
        int col = sN >> 4;
        int cig = (sN & 15) ^ (col & 15);
        const ushort* gp = z + ((size_t)(C0 + col) << 7) + (cig << 3);
        __builtin_amdgcn_global_load_lds(
            (const __attribute__((address_space(1))) void*)gp,
            (__attribute__((address_space(3))) void*)((char*)ldsB + sN * 16),
            16, 0, 0);
    }
    __syncthreads();   // single barrier: LDS written once per block

    // per-lane ds_read bases (ushort index): frag(st,kt) = c*128 + (((kt*4+q)^c)*8) + st*2048
    int xbase[4];
#pragma unroll
    for (int kt = 0; kt < 4; ++kt)
        xbase[kt] = c * 128 + ((((kt << 2) | q) ^ c) << 3);

    float rs[2][4], prow[2][4];
#pragma unroll
    for (int s = 0; s < 2; ++s)
#pragma unroll
        for (int r = 0; r < 4; ++r) { rs[s][r] = 0.f; prow[s][r] = 1.f; }

#pragma unroll
    for (int st = 0; st < 8; ++st) {
        f32x4 acc[2] = {{0.f, 0.f, 0.f, 0.f}, {0.f, 0.f, 0.f, 0.f}};
#pragma unroll
        for (int kt = 0; kt < 4; ++kt) {
            bf16x8 bf = *(const bf16x8*)(&ldsB[xbase[kt] + st * 2048]);
            acc[0] = __builtin_amdgcn_mfma_f32_16x16x32_bf16(afrag[0][kt], bf, acc[0], 0, 0, 0);
            acc[1] = __builtin_amdgcn_mfma_f32_16x16x32_bf16(afrag[1][kt], bf, acc[1], 0, 0, 0);
        }
        const int gc0 = C0 + st * 16;
        float sm = 0.f, pt = 1.f;   // col accumulators over this lane's 8 rows
#pragma unroll
        for (int s = 0; s < 2; ++s) {
            const int R = rowW + s * 16;
            float m[4], t[4];
#pragma unroll
            for (int r = 0; r < 4; ++r) {
                float u = acc[s][r];
                t[r] = 1.f + __builtin_amdgcn_exp2f(-fabsf(u));
                m[r] = fmaxf(u, 0.f);
            }
            if (diag && gc0 == R) {               // zero self-similarity
#pragma unroll
                for (int r = 0; r < 4; ++r)
                    if (c == q * 4 + r) { m[r] = 0.f; t[r] = 1.f; }
            }
            if (gc0 == (R ^ Bh)) {                // positive-pair subtile (rows < 8192)
#pragma unroll
                for (int r = 0; r < 4; ++r)
                    if (c == q * 4 + r)
                        pospair[R + q * 4 + r] = m[r] + __builtin_amdgcn_logf(t[r]);
            }
#pragma unroll
            for (int r = 0; r < 4; ++r) { rs[s][r] += m[r]; prow[s][r] *= t[r]; }
            if (!diag) {
                sm += (m[0] + m[1]) + (m[2] + m[3]);
                pt *= (t[0] * t[1]) * (t[2] * t[3]);
            }
        }
        if (!diag) {   // col credit: reduce over q (32 rows), ONE log2, atomic per col
            sm += __shfl_xor(sm, 16);
            sm += __shfl_xor(sm, 32);
            pt *= __shfl_xor(pt, 16);
            pt *= __shfl_xor(pt, 32);
            float ccred = sm + __builtin_amdgcn_logf(pt);
            if (lane < 16) atomicAdd(&rowsum[gc0 + c], ccred);
        }
    }

    // fold row products (8 logs), then flush row credits (one atomic per row)
#pragma unroll
    for (int s = 0; s < 2; ++s)
#pragma unroll
        for (int r = 0; r < 4; ++r) {
            float v = rs[s][r] + __builtin_amdgcn_logf(prow[s][r]);
            v += __shfl_xor(v, 1);
            v += __shfl_xor(v, 2);
            v += __shfl_xor(v, 4);
            v += __shfl_xor(v, 8);
            if (c == 0) atomicAdd(&rowsum[rowW + s * 16 + q * 4 + r], v);
        }

    // ---- fused finalize: last block to finish computes the loss ----
    __shared__ int lastflag;
    __threadfence();                       // release rowsum/pospair
    if (tid == 0) {
        int v = atomicAdd(cnt, 1);
        lastflag = (v == (int)gridDim.x - 1);
    }
    __syncthreads();
    if (lastflag) {
        __threadfence();                   // acquire all blocks' writes
        __shared__ float red[4];
        float acc = 0.f;
#pragma unroll 4
        for (int k = 0; k < 64; ++k) {
            int i = k * 256 + tid;
            float denom = fmaxf(LN2 * rowsum[i], EPS);
            float sp = fmaxf(LN2 * pospair[i & (Bh - 1)], EPS);  // pospair[i]==pospair[i^B]
            acc += __logf(sp) - __logf(denom);
        }
#pragma unroll
        for (int m = 1; m < 64; m <<= 1) acc += __shfl_xor(acc, m);
        if (lane == 0) red[wave] = acc;
        __syncthreads();
        if (tid == 0)
            out[0] = -(red[0] + red[1] + red[2] + red[3]) / (float)Nn;
    }
}

extern "C" void kernel_launch(void* const* d_in, const int* in_sizes, int n_in,
                              void* d_out, int out_size, void* d_ws, size_t ws_size,
                              hipStream_t stream) {
    const float* za = (const float*)d_in[0];
    const float* zb = (const float*)d_in[1];

    // workspace: z_bf16 (4 MB) | rowsum (64 KB) | pospair (32 KB) | counter
    ushort* z = (ushort*)d_ws;
    float* rowsum = (float*)((char*)d_ws + (size_t)Nn * Dd * 2);
    float* pospair = rowsum + Nn;
    int* cnt = (int*)(pospair + Bh);
    float* out = (float*)d_out;

    convert_kernel<<<2048, 256, 0, stream>>>((const float4*)za, (const float4*)zb, z, rowsum, cnt);
    main_kernel<<<N_TILES, 256, 0, stream>>>(z, rowsum, pospair, cnt, out);
}

// Round 11
// 269.147 us; speedup vs baseline: 2.3212x; 2.3212x over previous
//
#include <hip/hip_runtime.h>
#include <hip/hip_bf16.h>

// Problem constants (B=8192, D=128 from reference setup_inputs)
constexpr int Bh = 8192;
constexpr int Nn = 16384;   // 2*B
constexpr int Dd = 128;
constexpr float EPS = 1e-8f;
constexpr float LN2 = 0.69314718056f;

constexpr int K_TILES = 4;         // 128-col tiles per block
constexpr int N_TILES = 4160;      // upper-triangle 256x128 tiles: sum_b (128-2b)
constexpr int N_BLOCKS = N_TILES / K_TILES;   // 1040, exact

typedef short bf16x8 __attribute__((ext_vector_type(8)));
typedef float f32x4 __attribute__((ext_vector_type(4)));
typedef float f32x2 __attribute__((ext_vector_type(2)));

// ---- Kernel 1: fp32 -> bf16, scaled by sqrt(2*log2e) so MFMA dot == sim/tau*log2e ----
__global__ __launch_bounds__(256) void convert_kernel(const float4* __restrict__ za,
                                                      const float4* __restrict__ zb,
                                                      ushort* __restrict__ z,
                                                      float* __restrict__ rowsum,
                                                      int* __restrict__ cnt) {
    const int t = blockIdx.x * 256 + threadIdx.x;        // 0 .. 524287
    constexpr int Q = (Bh * Dd) / 4;                     // 262144 float4 per input
    const float SCL = 1.69864363f;                       // sqrt(2 * 1.4426950409)
    float4 v = (t < Q) ? za[t] : zb[t - Q];
    union { ushort4 u4; __hip_bfloat16 h[4]; } cv;
    cv.h[0] = __float2bfloat16(v.x * SCL);
    cv.h[1] = __float2bfloat16(v.y * SCL);
    cv.h[2] = __float2bfloat16(v.z * SCL);
    cv.h[3] = __float2bfloat16(v.w * SCL);
    ((ushort4*)z)[t] = cv.u4;
    if (t < Nn) rowsum[t] = 0.f;
    if (t == 0) *cnt = 0;    // last-block-done counter
}

// tile g -> 256-row block b: largest b with cum(b) = b*(129-b) <= g
__device__ __forceinline__ int row_block_of(int g) {
    int b = (int)((129.0f - sqrtf((float)(16641 - 4 * g))) * 0.5f);
    b = b < 0 ? 0 : (b > 63 ? 63 : b);
    while (b * (129 - b) > g) --b;
    while ((b + 1) * (128 - b) <= g) ++b;
    return b;
}

// row-credit flush: reduce rs pairs over the 16 col-lanes, one atomic per row
__device__ __forceinline__ void flush_rs(float* __restrict__ rowsum, int rowW,
                                         f32x2 (&rs)[4][2], int q, int c) {
#pragma unroll
    for (int s = 0; s < 4; ++s)
#pragma unroll
        for (int p = 0; p < 2; ++p)
#pragma unroll
            for (int e = 0; e < 2; ++e) {
                float v = rs[s][p][e];
                v += __shfl_xor(v, 1);
                v += __shfl_xor(v, 2);
                v += __shfl_xor(v, 4);
                v += __shfl_xor(v, 8);
                if (c == 0) atomicAdd(&rowsum[rowW + s * 16 + q * 4 + p * 2 + e], v);
                rs[s][p][e] = 0.f;
            }
}

// ---- Kernel 2: symmetric upper-triangle (R6 geometry: 1040 blocks x 4 tiles,
// 4 waves x 64 rows, B streamed from L2, no LDS/barriers) + packed-f32 epilogue.
// R10 bug fixed: B prefetch uses the IMMUTABLE base bp + (st+1)*2048 (the R10
// pointer-mutation compounded: bp_st = bp0 + 2048*st(st+1)/2 -> OOB reads of
// 0xAA poison -> inf). st is fully unrolled; compiler strength-reduces anyway.
// Epilogue (R9 lesson: the invariant ~51 us/SIMD VALU busy IS the epilogue):
//   - product-softplus: softplus2(u)=max(u,0)+log2(t), t=1+2^-|u| (ONE exp2/elem;
//     logs deferred: 16/tile row-side, 1 per 16-col group/st col-side)
//   - f32x2 packed math (v_pk_add/mul/max_f32): 2 elems/instr, only exp2 scalar
//   - zero-C trick: first MFMA of each chain reads a loop-invariant zero vector
// NOTE: plain __launch_bounds__(256); min-waves args (R1/R5) clamp unified
// VGPR+AGPR to 64/128 and spill GBs to scratch.
__global__ __launch_bounds__(256) void main_kernel(const ushort* __restrict__ z,
                                                   float* __restrict__ rowsum,
                                                   float* __restrict__ pospair,
                                                   int* __restrict__ cnt,
                                                   float* __restrict__ out) {
    const int tid = threadIdx.x;
    const int wave = tid >> 6;
    const int lane = tid & 63;
    const int q = lane >> 4;        // quad: 0..3
    const int c = lane & 15;        // 0..15
    const int g0 = blockIdx.x * K_TILES;

    bf16x8 afrag[4][4];
    f32x2 rs[4][2];                 // row max-sums (pairs)
    f32x2 prow[4][2];               // row t-products (pairs)
    int cur_b = -1;
    int rowW = 0;

    const f32x4 zf = {0.f, 0.f, 0.f, 0.f};   // zero-C for MFMA chain heads
    const f32x2 one2 = {1.f, 1.f};
    const f32x2 zero2 = {0.f, 0.f};

#pragma unroll
    for (int s = 0; s < 4; ++s)
#pragma unroll
        for (int p = 0; p < 2; ++p) { rs[s][p] = zero2; prow[s][p] = one2; }

    for (int j = 0; j < K_TILES; ++j) {
        const int g = g0 + j;
        const int b = row_block_of(g);
        const int ct = 2 * b + (g - b * (129 - b));
        const int C0 = ct << 7;

        if (b != cur_b) {
            if (cur_b >= 0) flush_rs(rowsum, rowW, rs, q, c);
            cur_b = b;
            rowW = (b << 8) + wave * 64;
#pragma unroll
            for (int s = 0; s < 4; ++s) {
                const ushort* ap = z + (size_t)(rowW + s * 16 + c) * Dd;
#pragma unroll
                for (int kt = 0; kt < 4; ++kt)
                    afrag[s][kt] = *(const bf16x8*)(ap + kt * 32 + q * 8);
            }
        }

        const int rt = rowW >> 7;             // this wave's 128-row tile
        const bool skip = (ct < rt);          // below diagonal: mirror covers it
        const bool diag = (ct == rt);
        if (skip) continue;

        // per-lane B base (immutable): col = C0 + c, k-offset q*8; st stride 2048 elems
        const ushort* bp = z + ((size_t)(C0 + c) << 7) + (q << 3);

        bf16x8 bcur[4], bnxt[4];
#pragma unroll
        for (int kt = 0; kt < 4; ++kt) bcur[kt] = *(const bf16x8*)(bp + kt * 32);

#pragma unroll
        for (int st = 0; st < 8; ++st) {
            if (st < 7) {     // prefetch next st's B while this st computes
#pragma unroll
                for (int kt = 0; kt < 4; ++kt)
                    bnxt[kt] = *(const bf16x8*)(bp + (st + 1) * 2048 + kt * 32);
            }
            f32x4 acc[4];
#pragma unroll
            for (int s = 0; s < 4; ++s)
                acc[s] = __builtin_amdgcn_mfma_f32_16x16x32_bf16(afrag[s][0], bcur[0], zf, 0, 0, 0);
#pragma unroll
            for (int kt = 1; kt < 4; ++kt)
#pragma unroll
                for (int s = 0; s < 4; ++s)
                    acc[s] = __builtin_amdgcn_mfma_f32_16x16x32_bf16(afrag[s][kt], bcur[kt], acc[s], 0, 0, 0);

            const int gc0 = C0 + st * 16;
            f32x2 sm2 = zero2, pt2 = one2;    // packed col accumulators
#pragma unroll
            for (int s = 0; s < 4; ++s) {
                const int R = rowW + s * 16;
                f32x2 u01 = {acc[s][0], acc[s][1]};
                f32x2 u23 = {acc[s][2], acc[s][3]};
                f32x2 e01 = {__builtin_amdgcn_exp2f(-fabsf(u01[0])),
                             __builtin_amdgcn_exp2f(-fabsf(u01[1]))};
                f32x2 e23 = {__builtin_amdgcn_exp2f(-fabsf(u23[0])),
                             __builtin_amdgcn_exp2f(-fabsf(u23[1]))};
                f32x2 m01 = __builtin_elementwise_max(u01, zero2);
                f32x2 m23 = __builtin_elementwise_max(u23, zero2);
                f32x2 t01 = e01 + one2;
                f32x2 t23 = e23 + one2;
                if (diag && gc0 == R) {               // zero self-similarity
#pragma unroll
                    for (int r = 0; r < 4; ++r)
                        if (c == q * 4 + r) {
                            if (r < 2) { m01[r] = 0.f; t01[r] = 1.f; }
                            else       { m23[r - 2] = 0.f; t23[r - 2] = 1.f; }
                        }
                }
                if (gc0 == (R ^ Bh)) {                // positive-pair subtile (rows<8192)
#pragma unroll
                    for (int r = 0; r < 4; ++r)
                        if (c == q * 4 + r) {
                            float mm = (r < 2) ? m01[r] : m23[r - 2];
                            float tt = (r < 2) ? t01[r] : t23[r - 2];
                            pospair[R + q * 4 + r] = mm + __builtin_amdgcn_logf(tt);
                        }
                }
                rs[s][0] += m01;  rs[s][1] += m23;        // pk adds
                prow[s][0] *= t01; prow[s][1] *= t23;     // pk muls
                if (!diag) {
                    sm2 += m01 + m23;                     // pk tree
                    pt2 *= t01 * t23;                     // pk tree
                }
            }
            if (!diag) {   // col credit: reduce over q (64 rows), ONE log2, atomic per col
                float sm = sm2[0] + sm2[1];
                float pt = pt2[0] * pt2[1];
                sm += __shfl_xor(sm, 16);
                sm += __shfl_xor(sm, 32);
                pt *= __shfl_xor(pt, 16);
                pt *= __shfl_xor(pt, 32);
                float ccred = sm + __builtin_amdgcn_logf(pt);
                if (lane < 16) atomicAdd(&rowsum[gc0 + c], ccred);
            }
            if (st < 7) {
#pragma unroll
                for (int kt = 0; kt < 4; ++kt) bcur[kt] = bnxt[kt];
            }
        }
        // tile end: fold row products into row sums (16 logs per tile)
#pragma unroll
        for (int s = 0; s < 4; ++s)
#pragma unroll
            for (int p = 0; p < 2; ++p) {
                rs[s][p][0] += __builtin_amdgcn_logf(prow[s][p][0]);
                rs[s][p][1] += __builtin_amdgcn_logf(prow[s][p][1]);
                prow[s][p] = one2;
            }
    }
    if (cur_b >= 0) flush_rs(rowsum, rowW, rs, q, c);

    // ---- fused finalize: last block to finish computes the loss ----
    __shared__ int lastflag;
    __threadfence();                       // release rowsum/pospair
    if (tid == 0) {
        int v = atomicAdd(cnt, 1);
        lastflag = (v == (int)gridDim.x - 1);
    }
    __syncthreads();
    if (lastflag) {
        __threadfence();                   // acquire all blocks' writes
        __shared__ float red[4];
        float acc = 0.f;
#pragma unroll 4
        for (int k = 0; k < 64; ++k) {
            int i = k * 256 + tid;
            float denom = fmaxf(LN2 * rowsum[i], EPS);
            float sp = fmaxf(LN2 * pospair[i & (Bh - 1)], EPS);  // pospair[i]==pospair[i^B]
            acc += __logf(sp) - __logf(denom);
        }
#pragma unroll
        for (int m = 1; m < 64; m <<= 1) acc += __shfl_xor(acc, m);
        if (lane == 0) red[wave] = acc;
        __syncthreads();
        if (tid == 0)
            out[0] = -(red[0] + red[1] + red[2] + red[3]) / (float)Nn;
    }
}

extern "C" void kernel_launch(void* const* d_in, const int* in_sizes, int n_in,
                              void* d_out, int out_size, void* d_ws, size_t ws_size,
                              hipStream_t stream) {
    const float* za = (const float*)d_in[0];
    const float* zb = (const float*)d_in[1];

    // workspace: z_bf16 (4 MB) | rowsum (64 KB) | pospair (32 KB) | counter
    ushort* z = (ushort*)d_ws;
    float* rowsum = (float*)((char*)d_ws + (size_t)Nn * Dd * 2);
    float* pospair = rowsum + Nn;
    int* cnt = (int*)(pospair + Bh);
    float* out = (float*)d_out;

    convert_kernel<<<2048, 256, 0, stream>>>((const float4*)za, (const float4*)zb, z, rowsum, cnt);
    main_kernel<<<N_BLOCKS, 256, 0, stream>>>(z, rowsum, pospair, cnt, out);
}